// Round 5
// baseline (306.607 us; speedup 1.0000x reference)
//
#include <hip/hip_runtime.h>

#define BATCH 32
#define LSEQ 4096
#define HDIM 512
#define PARTS 4
#define BLK_PER_B 32

typedef float f32x4 __attribute__((ext_vector_type(4)));

// -----------------------------------------------------------------------------
// Kernel 1: partial projection. grid (BATCH, PARTS), block 512.
// vpart[p][b][h] = sum_{o in slice p} h_last[b][o] * W[o][h]
// cpart[p][b]    = sum_{o in slice p} h_last[b][o] * bias[o]
// h_last[b,:] = hidden[0, 1, b, :] (flat offset (BATCH + b)*HDIM)
// -----------------------------------------------------------------------------
__global__ __launch_bounds__(512) void proj_kernel(
    const float* __restrict__ hidden, const float* __restrict__ W,
    const float* __restrict__ bias, float* __restrict__ vpart,
    float* __restrict__ cpart)
{
    const int b    = blockIdx.x;
    const int part = blockIdx.y;
    const int h    = threadIdx.x;
    const int OS   = HDIM / PARTS;          // 128
    const int obase = part * OS;

    __shared__ float s_hl[HDIM / PARTS];
    if (h < OS) s_hl[h] = hidden[(BATCH + b) * HDIM + obase + h];
    __syncthreads();

    float acc = 0.f;
#pragma unroll 16
    for (int o = 0; o < OS; ++o) {
        acc += s_hl[o] * W[(obase + o) * HDIM + h];   // coalesced across threads
    }
    vpart[(part * BATCH + b) * HDIM + h] = acc;

    // partial c
    float p = (h < OS) ? s_hl[h] * bias[obase + h] : 0.f;
#pragma unroll
    for (int off = 1; off < 64; off <<= 1) p += __shfl_xor(p, off, 64);

    __shared__ float red[8];
    const int wid  = h >> 6;
    const int lane = h & 63;
    if (lane == 0) red[wid] = p;
    __syncthreads();
    if (h == 0) {
        float s = 0.f;
#pragma unroll
        for (int w = 0; w < 8; ++w) s += red[w];
        cpart[part * BATCH + b] = s;
    }
}

// -----------------------------------------------------------------------------
// Kernel 2 (fused): energies[b,l] = enc[b,l,:] . v[b,:] + c[b], then the
// LAST-arriving block of each batch row runs the softmax for that row.
// Arrive-and-exit (no spin): zero deadlock risk, order-independent output.
// 16 lanes per row; 32 rows per wave; block 256 = 128 rows; 32 blocks per b.
// -----------------------------------------------------------------------------
__global__ __launch_bounds__(256) void energy_softmax_kernel(
    const float* __restrict__ enc, const float* __restrict__ vpart,
    const float* __restrict__ cpart, float* __restrict__ energies,
    unsigned int* __restrict__ counters)
{
    const int wave = threadIdx.x >> 6;
    const int lane = threadIdx.x & 63;
    const int sub  = lane >> 4;
    const int sl   = lane & 15;

    const int b      = blockIdx.x >> 5;            // 32 blocks per batch row
    const int l_base = (blockIdx.x & 31) * 128 + wave * 32;

    // hoist v = sum of 4 partials (L1/L2-resident)
    const f32x4* vp0 = (const f32x4*)(vpart + (0 * BATCH + b) * HDIM);
    const f32x4* vp1 = (const f32x4*)(vpart + (1 * BATCH + b) * HDIM);
    const f32x4* vp2 = (const f32x4*)(vpart + (2 * BATCH + b) * HDIM);
    const f32x4* vp3 = (const f32x4*)(vpart + (3 * BATCH + b) * HDIM);
    f32x4 vv[8];
#pragma unroll
    for (int k = 0; k < 8; ++k) {
        const int ch = sl + 16 * k;
        vv[k] = vp0[ch] + vp1[ch] + vp2[ch] + vp3[ch];
    }
    const float cb = cpart[b] + cpart[BATCH + b] + cpart[2 * BATCH + b]
                   + cpart[3 * BATCH + b];

    const long rbase = (long)b * LSEQ + l_base;

#pragma unroll 2
    for (int batch = 0; batch < 8; ++batch) {
        const long r = rbase + batch * 4 + sub;
        const f32x4* ep = (const f32x4*)(enc + r * HDIM) + sl;

        f32x4 e[8];
#pragma unroll
        for (int k = 0; k < 8; ++k)
            e[k] = __builtin_nontemporal_load(ep + 16 * k);

        float d = 0.f;
#pragma unroll
        for (int k = 0; k < 8; ++k) {
            d += e[k].x * vv[k].x + e[k].y * vv[k].y
               + e[k].z * vv[k].z + e[k].w * vv[k].w;
        }

        // reduce across the 16-lane group
        d += __shfl_xor(d, 1, 64);
        d += __shfl_xor(d, 2, 64);
        d += __shfl_xor(d, 4, 64);
        d += __shfl_xor(d, 8, 64);

        if (sl == 0) energies[r] = d + cb;   // lanes 0,16,32,48 -> 16B segment
    }

    // ---- arrive: publish writes device-wide, count this block ----
    __threadfence();            // release our energy stores to agent scope
    __syncthreads();
    __shared__ unsigned int s_last;
    if (threadIdx.x == 0) {
        unsigned int old = __hip_atomic_fetch_add(
            &counters[b], 1u, __ATOMIC_ACQ_REL, __HIP_MEMORY_SCOPE_AGENT);
        s_last = (old == BLK_PER_B - 1) ? 1u : 0u;
    }
    __syncthreads();
    if (!s_last) return;

    // ---- last block for this b: softmax over energies[b, 0..4095] ----
    __threadfence();            // acquire: invalidate stale cached lines

    const int t = threadIdx.x;
    const int wid = t >> 6;
    float4* o4 = (float4*)(energies + (long)b * LSEQ);

    float4 vals[4];
    float m = -3.402823466e+38f;
#pragma unroll
    for (int i = 0; i < 4; ++i) {
        vals[i] = o4[i * 256 + t];
        m = fmaxf(m, fmaxf(fmaxf(vals[i].x, vals[i].y),
                           fmaxf(vals[i].z, vals[i].w)));
    }

    __shared__ float smax[4];
#pragma unroll
    for (int off = 1; off < 64; off <<= 1) m = fmaxf(m, __shfl_xor(m, off, 64));
    if (lane == 0) smax[wid] = m;
    __syncthreads();
    m = fmaxf(fmaxf(smax[0], smax[1]), fmaxf(smax[2], smax[3]));

    float s = 0.f;
#pragma unroll
    for (int i = 0; i < 4; ++i) {
        vals[i].x = __expf(vals[i].x - m);
        vals[i].y = __expf(vals[i].y - m);
        vals[i].z = __expf(vals[i].z - m);
        vals[i].w = __expf(vals[i].w - m);
        s += vals[i].x + vals[i].y + vals[i].z + vals[i].w;
    }
    __shared__ float ssum[4];
#pragma unroll
    for (int off = 1; off < 64; off <<= 1) s += __shfl_xor(s, off, 64);
    if (lane == 0) ssum[wid] = s;
    __syncthreads();
    s = ssum[0] + ssum[1] + ssum[2] + ssum[3];

    const float inv = 1.0f / s;
#pragma unroll
    for (int i = 0; i < 4; ++i) {
        float4 w = vals[i];
        w.x *= inv; w.y *= inv; w.z *= inv; w.w *= inv;
        o4[i * 256 + t] = w;
    }
}

// -----------------------------------------------------------------------------
extern "C" void kernel_launch(void* const* d_in, const int* in_sizes, int n_in,
                              void* d_out, int out_size, void* d_ws, size_t ws_size,
                              hipStream_t stream)
{
    const float* hidden = (const float*)d_in[0];   // (2,2,B,H)
    const float* enc    = (const float*)d_in[1];   // (B,L,H)
    const float* W      = (const float*)d_in[2];   // (H,H)
    const float* bias   = (const float*)d_in[3];   // (H,)

    float* ws = (float*)d_ws;
    unsigned int* counters = (unsigned int*)ws;      // 32 u32 (zeroed below)
    float* vpart = ws + 64;                          // PARTS*B*H floats
    float* cpart = vpart + PARTS * BATCH * HDIM;     // PARTS*B floats

    float* out = (float*)d_out;                      // B*L floats

    hipMemsetAsync(counters, 0, BATCH * sizeof(unsigned int), stream);
    proj_kernel<<<dim3(BATCH, PARTS), 512, 0, stream>>>(hidden, W, bias, vpart, cpart);
    energy_softmax_kernel<<<(BATCH * LSEQ) / 128, 256, 0, stream>>>(
        enc, vpart, cpart, out, counters);
}

// Round 6
// 56.378 us; speedup vs baseline: 5.4384x; 5.4384x over previous
//
#include <hip/hip_runtime.h>

#define BATCH 32
#define LSEQ 4096
#define HDIM 512
#define PARTS 4

typedef float f32x4 __attribute__((ext_vector_type(4)));

// -----------------------------------------------------------------------------
// Kernel 1: partial projection. grid (BATCH, PARTS), block 512.
// vpart[p][b][h] = sum_{o in slice p} h_last[b][o] * W[o][h]
// cpart[p][b]    = sum_{o in slice p} h_last[b][o] * bias[o]
// h_last[b,:] = hidden[0, 1, b, :] (flat offset (BATCH + b)*HDIM)
// -----------------------------------------------------------------------------
__global__ __launch_bounds__(512) void proj_kernel(
    const float* __restrict__ hidden, const float* __restrict__ W,
    const float* __restrict__ bias, float* __restrict__ vpart,
    float* __restrict__ cpart)
{
    const int b    = blockIdx.x;
    const int part = blockIdx.y;
    const int h    = threadIdx.x;
    const int OS   = HDIM / PARTS;          // 128
    const int obase = part * OS;

    __shared__ float s_hl[HDIM / PARTS];
    if (h < OS) s_hl[h] = hidden[(BATCH + b) * HDIM + obase + h];
    __syncthreads();

    float acc = 0.f;
#pragma unroll 16
    for (int o = 0; o < OS; ++o) {
        acc += s_hl[o] * W[(obase + o) * HDIM + h];   // coalesced across threads
    }
    vpart[(part * BATCH + b) * HDIM + h] = acc;

    // partial c
    float p = (h < OS) ? s_hl[h] * bias[obase + h] : 0.f;
#pragma unroll
    for (int off = 1; off < 64; off <<= 1) p += __shfl_xor(p, off, 64);

    __shared__ float red[8];
    const int wid  = h >> 6;
    const int lane = h & 63;
    if (lane == 0) red[wid] = p;
    __syncthreads();
    if (h == 0) {
        float s = 0.f;
#pragma unroll
        for (int w = 0; w < 8; ++w) s += red[w];
        cpart[part * BATCH + b] = s;
    }
}

// -----------------------------------------------------------------------------
// Kernel 2: energies[b,l] = enc[b,l,:] . v[b,:] + c[b]
// 16 lanes per row (sub = lane>>4 picks row, sl = lane&15 picks chunk).
// Plain (cache-allocating) loads: enc is exactly L3-sized, graph replays
// hit Infinity Cache for ~half the stream (measured R5: FETCH 132/268 MB).
// v = sum of 4 proj partials hoisted once per wave. 32 rows/wave,
// block 256 = 128 rows, grid 1024.
// -----------------------------------------------------------------------------
__global__ __launch_bounds__(256) void energy_kernel(
    const float* __restrict__ enc, const float* __restrict__ vpart,
    const float* __restrict__ cpart, float* __restrict__ energies)
{
    const int wave = threadIdx.x >> 6;
    const int lane = threadIdx.x & 63;
    const int sub  = lane >> 4;
    const int sl   = lane & 15;

    const int b      = blockIdx.x >> 5;            // 32 blocks per batch row
    const int l_base = (blockIdx.x & 31) * 128 + wave * 32;

    // hoist v = sum of 4 partials (L1/L2-resident)
    const f32x4* vp0 = (const f32x4*)(vpart + (0 * BATCH + b) * HDIM);
    const f32x4* vp1 = (const f32x4*)(vpart + (1 * BATCH + b) * HDIM);
    const f32x4* vp2 = (const f32x4*)(vpart + (2 * BATCH + b) * HDIM);
    const f32x4* vp3 = (const f32x4*)(vpart + (3 * BATCH + b) * HDIM);
    f32x4 vv[8];
#pragma unroll
    for (int k = 0; k < 8; ++k) {
        const int ch = sl + 16 * k;
        vv[k] = vp0[ch] + vp1[ch] + vp2[ch] + vp3[ch];
    }
    const float cb = cpart[b] + cpart[BATCH + b] + cpart[2 * BATCH + b]
                   + cpart[3 * BATCH + b];

    const long rbase = (long)b * LSEQ + l_base;

#pragma unroll 2
    for (int batch = 0; batch < 8; ++batch) {
        const long r = rbase + batch * 4 + sub;
        const f32x4* ep = (const f32x4*)(enc + r * HDIM) + sl;

        f32x4 e[8];
#pragma unroll
        for (int k = 0; k < 8; ++k)
            e[k] = ep[16 * k];

        float d = 0.f;
#pragma unroll
        for (int k = 0; k < 8; ++k) {
            d += e[k].x * vv[k].x + e[k].y * vv[k].y
               + e[k].z * vv[k].z + e[k].w * vv[k].w;
        }

        // reduce across the 16-lane group
        d += __shfl_xor(d, 1, 64);
        d += __shfl_xor(d, 2, 64);
        d += __shfl_xor(d, 4, 64);
        d += __shfl_xor(d, 8, 64);

        if (sl == 0) energies[r] = d + cb;   // lanes 0,16,32,48 -> 16B segment
    }
}

// -----------------------------------------------------------------------------
// Kernel 3: softmax over L per batch row, in place on d_out.
// 32 blocks x 1024 threads, 1 float4 per thread.
// -----------------------------------------------------------------------------
__global__ __launch_bounds__(1024) void softmax_kernel(float* __restrict__ out)
{
    const int b = blockIdx.x;
    const int t = threadIdx.x;
    const int wid  = t >> 6;
    const int lane = t & 63;

    float4* o4 = (float4*)(out + (long)b * LSEQ);

    float4 v0 = o4[t];
    float m = fmaxf(fmaxf(v0.x, v0.y), fmaxf(v0.z, v0.w));

    __shared__ float smax[16];
#pragma unroll
    for (int off = 1; off < 64; off <<= 1) m = fmaxf(m, __shfl_xor(m, off, 64));
    if (lane == 0) smax[wid] = m;
    __syncthreads();
#pragma unroll
    for (int w = 0; w < 16; ++w) m = fmaxf(m, smax[w]);

    v0.x = __expf(v0.x - m); v0.y = __expf(v0.y - m);
    v0.z = __expf(v0.z - m); v0.w = __expf(v0.w - m);

    float s = v0.x + v0.y + v0.z + v0.w;
    __shared__ float ssum[16];
#pragma unroll
    for (int off = 1; off < 64; off <<= 1) s += __shfl_xor(s, off, 64);
    if (lane == 0) ssum[wid] = s;
    __syncthreads();
    s = 0.f;
#pragma unroll
    for (int w = 0; w < 16; ++w) s += ssum[w];

    const float inv = 1.0f / s;
    v0.x *= inv; v0.y *= inv; v0.z *= inv; v0.w *= inv;
    o4[t] = v0;
}

// -----------------------------------------------------------------------------
extern "C" void kernel_launch(void* const* d_in, const int* in_sizes, int n_in,
                              void* d_out, int out_size, void* d_ws, size_t ws_size,
                              hipStream_t stream)
{
    const float* hidden = (const float*)d_in[0];   // (2,2,B,H)
    const float* enc    = (const float*)d_in[1];   // (B,L,H)
    const float* W      = (const float*)d_in[2];   // (H,H)
    const float* bias   = (const float*)d_in[3];   // (H,)

    float* ws    = (float*)d_ws;
    float* vpart = ws;                               // PARTS*B*H floats
    float* cpart = ws + PARTS * BATCH * HDIM;        // PARTS*B floats

    float* out = (float*)d_out;                      // B*L floats (energies scratch)

    proj_kernel<<<dim3(BATCH, PARTS), 512, 0, stream>>>(hidden, W, bias, vpart, cpart);
    energy_kernel<<<(BATCH * LSEQ) / 128, 256, 0, stream>>>(enc, vpart, cpart, out);
    softmax_kernel<<<BATCH, 1024, 0, stream>>>(out);
}

// Round 7
// 55.719 us; speedup vs baseline: 5.5027x; 1.0118x over previous
//
#include <hip/hip_runtime.h>

#define BATCH 32
#define LSEQ 4096
#define HDIM 512
#define PARTS 4

typedef float f32x4 __attribute__((ext_vector_type(4)));

// -----------------------------------------------------------------------------
// Kernel 1: partial projection. grid (BATCH, PARTS), block 512.
// vpart[p][b][h] = sum_{o in slice p} h_last[b][o] * W[o][h]
// cpart[p][b]    = sum_{o in slice p} h_last[b][o] * bias[o]
// -----------------------------------------------------------------------------
__global__ __launch_bounds__(512) void proj_kernel(
    const float* __restrict__ hidden, const float* __restrict__ W,
    const float* __restrict__ bias, float* __restrict__ vpart,
    float* __restrict__ cpart)
{
    const int b    = blockIdx.x;
    const int part = blockIdx.y;
    const int h    = threadIdx.x;
    const int OS   = HDIM / PARTS;          // 128
    const int obase = part * OS;

    __shared__ float s_hl[HDIM / PARTS];
    if (h < OS) s_hl[h] = hidden[(BATCH + b) * HDIM + obase + h];
    __syncthreads();

    float acc = 0.f;
#pragma unroll 16
    for (int o = 0; o < OS; ++o) {
        acc += s_hl[o] * W[(obase + o) * HDIM + h];
    }
    vpart[(part * BATCH + b) * HDIM + h] = acc;

    float p = (h < OS) ? s_hl[h] * bias[obase + h] : 0.f;
#pragma unroll
    for (int off = 1; off < 64; off <<= 1) p += __shfl_xor(p, off, 64);

    __shared__ float red[8];
    const int wid  = h >> 6;
    const int lane = h & 63;
    if (lane == 0) red[wid] = p;
    __syncthreads();
    if (h == 0) {
        float s = 0.f;
#pragma unroll
        for (int w = 0; w < 8; ++w) s += red[w];
        cpart[part * BATCH + b] = s;
    }
}

// -----------------------------------------------------------------------------
// Kernel 2: energies[b,l] = enc[b,l,:] . v[b,:] + c[b]
// L3-pinning split: b < 16 uses plain loads (allocate in Infinity Cache ->
// 128 MB stays resident across graph replays); b >= 16 uses nontemporal
// (stream from HBM, don't thrash the resident half).
// 16 lanes per row; 32 rows/wave; block 256 = 128 rows; grid 1024.
// -----------------------------------------------------------------------------
__global__ __launch_bounds__(256) void energy_kernel(
    const float* __restrict__ enc, const float* __restrict__ vpart,
    const float* __restrict__ cpart, float* __restrict__ energies)
{
    const int wave = threadIdx.x >> 6;
    const int lane = threadIdx.x & 63;
    const int sub  = lane >> 4;
    const int sl   = lane & 15;

    const int b      = blockIdx.x >> 5;
    const int l_base = (blockIdx.x & 31) * 128 + wave * 32;

    const f32x4* vp0 = (const f32x4*)(vpart + (0 * BATCH + b) * HDIM);
    const f32x4* vp1 = (const f32x4*)(vpart + (1 * BATCH + b) * HDIM);
    const f32x4* vp2 = (const f32x4*)(vpart + (2 * BATCH + b) * HDIM);
    const f32x4* vp3 = (const f32x4*)(vpart + (3 * BATCH + b) * HDIM);
    f32x4 vv[8];
#pragma unroll
    for (int k = 0; k < 8; ++k) {
        const int ch = sl + 16 * k;
        vv[k] = vp0[ch] + vp1[ch] + vp2[ch] + vp3[ch];
    }
    const float cb = cpart[b] + cpart[BATCH + b] + cpart[2 * BATCH + b]
                   + cpart[3 * BATCH + b];

    const long rbase = (long)b * LSEQ + l_base;
    const bool resident_half = (b < BATCH / 2);

#pragma unroll 2
    for (int batch = 0; batch < 8; ++batch) {
        const long r = rbase + batch * 4 + sub;
        const f32x4* ep = (const f32x4*)(enc + r * HDIM) + sl;

        f32x4 e[8];
        if (resident_half) {
#pragma unroll
            for (int k = 0; k < 8; ++k)
                e[k] = ep[16 * k];                       // allocate in L3
        } else {
#pragma unroll
            for (int k = 0; k < 8; ++k)
                e[k] = __builtin_nontemporal_load(ep + 16 * k);  // stream
        }

        float d = 0.f;
#pragma unroll
        for (int k = 0; k < 8; ++k) {
            d += e[k].x * vv[k].x + e[k].y * vv[k].y
               + e[k].z * vv[k].z + e[k].w * vv[k].w;
        }

        d += __shfl_xor(d, 1, 64);
        d += __shfl_xor(d, 2, 64);
        d += __shfl_xor(d, 4, 64);
        d += __shfl_xor(d, 8, 64);

        if (sl == 0) energies[r] = d + cb;
    }
}

// -----------------------------------------------------------------------------
// Kernel 3: softmax over L per batch row, in place on d_out.
// 32 blocks x 1024 threads, 1 float4 per thread.
// -----------------------------------------------------------------------------
__global__ __launch_bounds__(1024) void softmax_kernel(float* __restrict__ out)
{
    const int b = blockIdx.x;
    const int t = threadIdx.x;
    const int wid  = t >> 6;
    const int lane = t & 63;

    float4* o4 = (float4*)(out + (long)b * LSEQ);

    float4 v0 = o4[t];
    float m = fmaxf(fmaxf(v0.x, v0.y), fmaxf(v0.z, v0.w));

    __shared__ float smax[16];
#pragma unroll
    for (int off = 1; off < 64; off <<= 1) m = fmaxf(m, __shfl_xor(m, off, 64));
    if (lane == 0) smax[wid] = m;
    __syncthreads();
#pragma unroll
    for (int w = 0; w < 16; ++w) m = fmaxf(m, smax[w]);

    v0.x = __expf(v0.x - m); v0.y = __expf(v0.y - m);
    v0.z = __expf(v0.z - m); v0.w = __expf(v0.w - m);

    float s = v0.x + v0.y + v0.z + v0.w;
    __shared__ float ssum[16];
#pragma unroll
    for (int off = 1; off < 64; off <<= 1) s += __shfl_xor(s, off, 64);
    if (lane == 0) ssum[wid] = s;
    __syncthreads();
    s = 0.f;
#pragma unroll
    for (int w = 0; w < 16; ++w) s += ssum[w];

    const float inv = 1.0f / s;
    v0.x *= inv; v0.y *= inv; v0.z *= inv; v0.w *= inv;
    o4[t] = v0;
}

// -----------------------------------------------------------------------------
extern "C" void kernel_launch(void* const* d_in, const int* in_sizes, int n_in,
                              void* d_out, int out_size, void* d_ws, size_t ws_size,
                              hipStream_t stream)
{
    const float* hidden = (const float*)d_in[0];   // (2,2,B,H)
    const float* enc    = (const float*)d_in[1];   // (B,L,H)
    const float* W      = (const float*)d_in[2];   // (H,H)
    const float* bias   = (const float*)d_in[3];   // (H,)

    float* ws    = (float*)d_ws;
    float* vpart = ws;                               // PARTS*B*H floats
    float* cpart = ws + PARTS * BATCH * HDIM;        // PARTS*B floats

    float* out = (float*)d_out;                      // B*L floats

    proj_kernel<<<dim3(BATCH, PARTS), 512, 0, stream>>>(hidden, W, bias, vpart, cpart);
    energy_kernel<<<(BATCH * LSEQ) / 128, 256, 0, stream>>>(enc, vpart, cpart, out);
    softmax_kernel<<<BATCH, 1024, 0, stream>>>(out);
}